// Round 9
// baseline (953.395 us; speedup 1.0000x reference)
//
#include <hip/hip_runtime.h>
#include <cstdint>

#define B_    512
#define T_    64
#define VOCAB_ 10000
#define VPAD_ 10112     // vocab padded to 128
#define EMB_  512
#define HID_  1024
#define G4H_  4096      // 4*HID
#define KCAT_ 1536      // EMB + HID
#define NIMG_ 2048

typedef _Float16 half8 __attribute__((ext_vector_type(8)));
typedef _Float16 half4 __attribute__((ext_vector_type(4)));
typedef float floatx4 __attribute__((ext_vector_type(4)));

// Async global->LDS, 16B per lane. LDS dest = wave-uniform base (HW adds
// lane*16). Per-lane SOURCE address is free (gather OK).
__device__ __forceinline__ void async_copy16(void* lds_uniform, const void* gsrc) {
    __builtin_amdgcn_global_load_lds(
        (__attribute__((address_space(1))) void*)(uintptr_t)gsrc,
        (__attribute__((address_space(3))) void*)(uint32_t)(uintptr_t)lds_uniform,
        16, 0, 0);
}

__device__ __forceinline__ float fsig(float x)  { return 1.0f / (1.0f + __expf(-x)); }
__device__ __forceinline__ float ftanh(float x) { return 1.0f - 2.0f / (__expf(2.0f * x) + 1.0f); }

// Gate-interleaved weight-row permutation:
//   n_perm = jblk*64 + gate*16 + jlo   <->   n_orig = gate*HID + (jblk*16 + jlo)

// ---------------------------------------------------------------------------
// One-time: emb->f16, Wc16 = permuted [W_ih|W_hh] (4096 x 1536), Wout16,
// biasp = permuted (b_ih+b_hh), Hseq[0] = 0, tokperm[t*B+b] = m[b][t].
// ---------------------------------------------------------------------------
__global__ __launch_bounds__(256) void convert_kernel(
    const int* __restrict__ m, const float* __restrict__ emb,
    const float* __restrict__ W_ih, const float* __restrict__ W_hh,
    const float* __restrict__ b_ih, const float* __restrict__ b_hh,
    const float* __restrict__ W_out,
    _Float16* __restrict__ emb16, _Float16* __restrict__ Wc16,
    _Float16* __restrict__ Wout16, float* __restrict__ biasp,
    _Float16* __restrict__ Hseq, int* __restrict__ tokperm)
{
    const long long EMB_N = (long long)VOCAB_ * EMB_;
    const long long WC_N  = (long long)G4H_ * KCAT_;
    const long long WO_N  = (long long)NIMG_ * HID_;
    const long long BI_N  = G4H_;
    const long long ST_N  = (long long)B_ * HID_;
    const long long TK_N  = (long long)B_ * T_;

    long long i = (long long)blockIdx.x * 256 + threadIdx.x;
    if (i < EMB_N) { emb16[i] = (_Float16)emb[i]; return; }
    i -= EMB_N;
    if (i < WC_N) {
        int n_perm = (int)(i / KCAT_);
        int k      = (int)(i % KCAT_);
        int gate = (n_perm >> 4) & 3;
        int j    = (n_perm >> 6) * 16 + (n_perm & 15);
        int n_orig = gate * HID_ + j;
        float v = (k < EMB_) ? W_ih[(size_t)n_orig * EMB_ + k]
                             : W_hh[(size_t)n_orig * HID_ + (k - EMB_)];
        Wc16[i] = (_Float16)v;
        return;
    }
    i -= WC_N;
    if (i < WO_N) { Wout16[i] = (_Float16)W_out[i]; return; }
    i -= WO_N;
    if (i < BI_N) {
        int n_perm = (int)i;
        int gate = (n_perm >> 4) & 3;
        int j    = (n_perm >> 6) * 16 + (n_perm & 15);
        biasp[i] = b_ih[gate * HID_ + j] + b_hh[gate * HID_ + j];
        return;
    }
    i -= BI_N;
    if (i < ST_N) { Hseq[i] = (_Float16)0.0f; return; }   // Hseq[0] = h_0 = 0
    i -= ST_N;
    if (i < TK_N) {
        int t = (int)(i / B_), b = (int)(i % B_);
        tokperm[i] = m[(size_t)b * T_ + t];
    }
}

// ---------------------------------------------------------------------------
// PE table GEMM: PEx[v][jblk*64 + jlo*4 + g] = emb[v] @ W_ih_perm^T + biasp
// (gate-packed: persistent kernel's acc-init is one 8B load per row).
// ---------------------------------------------------------------------------
__global__ __launch_bounds__(256) void gemm_pe(
    const _Float16* __restrict__ emb16, const _Float16* __restrict__ Wc16,
    const float* __restrict__ biasp, _Float16* __restrict__ PEx)
{
    __shared__ __align__(16) _Float16 As[128 * 32];
    __shared__ __align__(16) _Float16 Bs[128 * 32];

    const int tid  = threadIdx.x;
    const int wid  = tid >> 6;
    const int lane = tid & 63;
    const int lcol = lane & 15;
    const int quad = lane >> 4;
    const int wm   = wid >> 1;
    const int wn   = wid & 1;

    const int r0 = blockIdx.x * 128;
    const int n0 = blockIdx.y * 128;

    floatx4 acc[4][4];
#pragma unroll
    for (int i = 0; i < 4; ++i)
#pragma unroll
        for (int j = 0; j < 4; ++j) acc[i][j] = (floatx4){0.f, 0.f, 0.f, 0.f};

    const int ar = tid >> 2;
    const int kq = tid & 3;

    for (int k0 = 0; k0 < EMB_; k0 += 32) {
        async_copy16((char*)As + (wid << 10),
                     emb16 + (size_t)(r0 + ar) * EMB_ + (k0 + kq * 8));
        async_copy16((char*)As + 4096 + (wid << 10),
                     emb16 + (size_t)(r0 + 64 + ar) * EMB_ + (k0 + kq * 8));
        async_copy16((char*)Bs + (wid << 10),
                     Wc16 + (size_t)(n0 + ar) * KCAT_ + (k0 + kq * 8));
        async_copy16((char*)Bs + 4096 + (wid << 10),
                     Wc16 + (size_t)(n0 + 64 + ar) * KCAT_ + (k0 + kq * 8));
        __syncthreads();

        half8 af[4], bf[4];
#pragma unroll
        for (int mi = 0; mi < 4; ++mi)
            af[mi] = *(const half8*)&As[(wm * 64 + mi * 16 + lcol) * 32 + quad * 8];
#pragma unroll
        for (int ni = 0; ni < 4; ++ni)
            bf[ni] = *(const half8*)&Bs[(wn * 64 + ni * 16 + lcol) * 32 + quad * 8];
#pragma unroll
        for (int mi = 0; mi < 4; ++mi)
#pragma unroll
            for (int ni = 0; ni < 4; ++ni)
                acc[mi][ni] = __builtin_amdgcn_mfma_f32_16x16x32_f16(
                    af[mi], bf[ni], acc[mi][ni], 0, 0, 0);
        __syncthreads();
    }

    const int jblk = (n0 + wn * 64) >> 6;
    float bv[4];
#pragma unroll
    for (int ni = 0; ni < 4; ++ni) bv[ni] = biasp[n0 + wn * 64 + ni * 16 + lcol];
#pragma unroll
    for (int mi = 0; mi < 4; ++mi) {
#pragma unroll
        for (int r = 0; r < 4; ++r) {
            const int row = r0 + wm * 64 + mi * 16 + quad * 4 + r;
            half4 v;
#pragma unroll
            for (int ni = 0; ni < 4; ++ni)
                v[ni] = (_Float16)(acc[mi][ni][r] + bv[ni]);
            *(half4*)(PEx + (size_t)row * G4H_ + jblk * 64 + lcol * 4) = v;
        }
    }
}

// ---------------------------------------------------------------------------
// Persistent LSTM. Grid (4,64)=256 blocks, 1/CU. Tile 128 rows x 64 perm-cols.
// R8 change vs R7 (sync granularity only — zero-fence scheme kept):
//  * PER-CHUNK producer gating: K-chunk s (k=32s..32s+31) only needs the two
//    producers by'=2s,2s+1 of gang bx. One 64-lane ballot refresh gives the
//    readiness mask; a chunk re-polls only if ITS pair is missing. Chunk
//    order rotated by `by` so consumers start on different pairs.
//  R7's residual: every block waited for max-of-64 producers each step
//  (straggler tail ~4-8us/step). Now only the dependent chunk waits, and the
//  other 31 chunks' compute absorbs the tail.
// ---------------------------------------------------------------------------
__global__ __launch_bounds__(256, 1) void lstm_persistent(
    const _Float16* __restrict__ PEx, const int* __restrict__ tokperm,
    const _Float16* __restrict__ Wc16,
    _Float16* __restrict__ Hseq,
    unsigned* __restrict__ flags)
{
    __shared__ __align__(16) char Wlds[131072];   // frag-major, 128 KB

    const int tid  = threadIdx.x;
    const int wid  = tid >> 6;
    const int lane = tid & 63;
    const int lcol = lane & 15;
    const int quad = lane >> 4;
    const int bx   = blockIdx.x;
    const int b0   = bx * 128;
    const int by   = blockIdx.y;
    const int n0   = by * 64;

    // One-time cross-launch safety: clear any stale lines (cheap, once).
    __builtin_amdgcn_fence(__ATOMIC_ACQUIRE, "agent");

    // ---- W one-time load, fragment-major: Wlds[((s*4+g)*64+lane)*16] holds
    // B-frag element W[n0+g*16+lcol][EMB + s*32+quad*8 ..+7]. Wave wid
    // handles s in [wid*8, wid*8+8). Conflict-free by construction.
    for (int si = 0; si < 8; ++si) {
        const int s = wid * 8 + si;
#pragma unroll
        for (int g = 0; g < 4; ++g) {
            half8 v = *(const half8*)(Wc16 + (size_t)(n0 + g * 16 + lcol) * KCAT_
                                      + EMB_ + s * 32 + quad * 8);
            *(half8*)(Wlds + (((s * 4 + g) << 6) + lane) * 16) = v;
        }
    }

    // Thread's outputs: rows wid*32+mi*16+quad*4+r (mi 0..1), col j=by*16+lcol
    float cst[2][4] = {{0.f, 0.f, 0.f, 0.f}, {0.f, 0.f, 0.f, 0.f}};
    half4 pe[2][4];

    // PE prefetch for t=0
#pragma unroll
    for (int mi = 0; mi < 2; ++mi)
#pragma unroll
        for (int r = 0; r < 4; ++r) {
            const int row = wid * 32 + mi * 16 + quad * 4 + r;
            const int tk = tokperm[b0 + row];
            pe[mi][r] = *(const half4*)(PEx + (size_t)tk * G4H_ + by * 64 + lcol * 4);
        }

    __syncthreads();  // W in LDS visible to all waves

    const int wrow = wid * 32;

    for (int t = 0; t < T_; ++t) {
        const _Float16* h_prev = Hseq + (size_t)t * (B_ * HID_);
        _Float16*       h_next = Hseq + (size_t)(t + 1) * (B_ * HID_);

        const unsigned want = 0x5AB00000u + (unsigned)(t - 1);
        const unsigned* f = flags + ((size_t)(t > 0 ? t - 1 : 0) * 4 + bx) * 64;

        // readiness mask over the 64 same-bx producers of step t-1
        unsigned long long rdy = (t == 0) ? ~0ull : 0ull;

        // A-fragment source rows (plain cached loads on FRESH lines)
        const _Float16* arow0 = h_prev + (size_t)(b0 + wrow + lcol) * HID_ + quad * 8;
        const _Float16* arow1 = arow0 + (size_t)16 * HID_;

        floatx4 acc[2][4];
#pragma unroll
        for (int mi = 0; mi < 2; ++mi)
#pragma unroll
            for (int g = 0; g < 4; ++g)
#pragma unroll
                for (int r = 0; r < 4; ++r)
                    acc[mi][g][r] = (float)pe[mi][r][g];

        // wait until producer pair p (by' = 2p, 2p+1) has published
        auto waitp = [&](int p) {
            if (((rdy >> (2 * p)) & 3ull) == 3ull) return;
            for (;;) {
                rdy = __ballot((int)(__hip_atomic_load(&f[lane], __ATOMIC_RELAXED,
                                                       __HIP_MEMORY_SCOPE_AGENT) == want));
                if (((rdy >> (2 * p)) & 3ull) == 3ull) break;
                __builtin_amdgcn_s_sleep(1);
            }
            asm volatile("" ::: "memory");  // no hoisting of h loads above poll
        };

        // ---- per-chunk-gated, depth-8 register pipeline; chunk order
        // rotated by `by` so consumers start on different producer pairs ----
        half8 pa0[8], pa1[8];
#pragma unroll
        for (int c = 0; c < 8; ++c) {
            const int cs = (c + by) & 31;
            waitp(cs);
            pa0[c] = *(const half8*)(arow0 + cs * 32);
            pa1[c] = *(const half8*)(arow1 + cs * 32);
        }
#pragma unroll
        for (int s = 0; s < 32; ++s) {
            const int cs = (s + by) & 31;       // actual k-chunk for this iter
            const half8 a0 = pa0[s & 7];
            const half8 a1 = pa1[s & 7];
            if (s + 8 < 32) {
                const int cs8 = (s + 8 + by) & 31;
                waitp(cs8);
                pa0[s & 7] = *(const half8*)(arow0 + cs8 * 32);
                pa1[s & 7] = *(const half8*)(arow1 + cs8 * 32);
            }
#pragma unroll
            for (int g = 0; g < 4; ++g) {
                const half8 bw = *(const half8*)(Wlds + (((cs * 4 + g) << 6) + lane) * 16);
                acc[0][g] = __builtin_amdgcn_mfma_f32_16x16x32_f16(a0, bw, acc[0][g], 0, 0, 0);
                acc[1][g] = __builtin_amdgcn_mfma_f32_16x16x32_f16(a1, bw, acc[1][g], 0, 0, 0);
            }
        }

        // ---- fused LSTM cell; h written WRITE-THROUGH to LLC (2B relaxed
        // agent atomic stores; no wbl2 needed at publish) ----
#pragma unroll
        for (int mi = 0; mi < 2; ++mi)
#pragma unroll
            for (int r = 0; r < 4; ++r) {
                const int row = wrow + mi * 16 + quad * 4 + r;
                const float iv = fsig(acc[mi][0][r]);
                const float fv = fsig(acc[mi][1][r]);
                const float gv = ftanh(acc[mi][2][r]);
                const float ov = fsig(acc[mi][3][r]);
                cst[mi][r] = fv * cst[mi][r] + iv * gv;
                const _Float16 hv = (_Float16)(ov * ftanh(cst[mi][r]));
                unsigned short us = __builtin_bit_cast(unsigned short, hv);
                __hip_atomic_store(
                    (unsigned short*)&h_next[(size_t)(b0 + row) * HID_ + by * 16 + lcol],
                    us, __ATOMIC_RELAXED, __HIP_MEMORY_SCOPE_AGENT);
            }

        // ---- publish: drain stores (syncthreads waits vmcnt 0), then one
        // relaxed flag store by tid0. NO fences. ----
        __syncthreads();
        if (tid == 0) {
            __hip_atomic_store(&flags[((size_t)t * 4 + bx) * 64 + by],
                               0x5AB00000u + (unsigned)t,
                               __ATOMIC_RELAXED, __HIP_MEMORY_SCOPE_AGENT);
        }

        // PE prefetch for t+1 (read-only cached data; overlaps others' polls)
        if (t + 1 < T_) {
#pragma unroll
            for (int mi = 0; mi < 2; ++mi)
#pragma unroll
                for (int r = 0; r < 4; ++r) {
                    const int row = wrow + mi * 16 + quad * 4 + r;
                    const int tk = tokperm[(t + 1) * B_ + b0 + row];
                    pe[mi][r] = *(const half4*)(PEx + (size_t)tk * G4H_ + by * 64 + lcol * 4);
                }
        }
    }
}

// ---------------------------------------------------------------------------
// Final projection GEMM (unpermuted): Out = h @ Wout16^T + b_out
// ---------------------------------------------------------------------------
__global__ __launch_bounds__(256) void gemm_out(
    const _Float16* __restrict__ A, const _Float16* __restrict__ Bw,
    const float* __restrict__ bias, float* __restrict__ Out, int N, int K)
{
    __shared__ __align__(16) _Float16 As[64 * 32];
    __shared__ __align__(16) _Float16 Bs[128 * 32];

    const int tid  = threadIdx.x;
    const int wid  = tid >> 6;
    const int lane = tid & 63;
    const int lcol = lane & 15;
    const int quad = lane >> 4;
    const int wm   = wid >> 1;
    const int wn   = wid & 1;

    const int b0 = blockIdx.x * 64;
    const int n0 = blockIdx.y * 128;

    floatx4 acc[2][4];
#pragma unroll
    for (int i = 0; i < 2; ++i)
#pragma unroll
        for (int j = 0; j < 4; ++j) acc[i][j] = (floatx4){0.f, 0.f, 0.f, 0.f};

    const int ar = tid >> 2;
    const int kq = tid & 3;

    for (int k0 = 0; k0 < K; k0 += 32) {
        async_copy16((char*)As + (wid << 10), A + (size_t)(b0 + ar) * K + (k0 + kq * 8));
        async_copy16((char*)Bs + (wid << 10), Bw + (size_t)(n0 + ar) * K + (k0 + kq * 8));
        async_copy16((char*)Bs + 4096 + (wid << 10),
                     Bw + (size_t)(n0 + 64 + ar) * K + (k0 + kq * 8));
        __syncthreads();

        half8 af[2], bfr[4];
#pragma unroll
        for (int mi = 0; mi < 2; ++mi)
            af[mi] = *(const half8*)&As[(wm * 32 + mi * 16 + lcol) * 32 + quad * 8];
#pragma unroll
        for (int ni = 0; ni < 4; ++ni)
            bfr[ni] = *(const half8*)&Bs[(wn * 64 + ni * 16 + lcol) * 32 + quad * 8];
#pragma unroll
        for (int mi = 0; mi < 2; ++mi)
#pragma unroll
            for (int ni = 0; ni < 4; ++ni)
                acc[mi][ni] = __builtin_amdgcn_mfma_f32_16x16x32_f16(
                    af[mi], bfr[ni], acc[mi][ni], 0, 0, 0);
        __syncthreads();
    }

#pragma unroll
    for (int mi = 0; mi < 2; ++mi) {
#pragma unroll
        for (int ni = 0; ni < 4; ++ni) {
            const int row = b0 + wm * 32 + mi * 16 + quad * 4;
            const int col = n0 + wn * 64 + ni * 16 + lcol;
            const float bv = bias[col];
#pragma unroll
            for (int r = 0; r < 4; ++r)
                Out[(size_t)(row + r) * N + col] = acc[mi][ni][r] + bv;
        }
    }
}

// ---------------------------------------------------------------------------
extern "C" void kernel_launch(void* const* d_in, const int* in_sizes, int n_in,
                              void* d_out, int out_size, void* d_ws, size_t ws_size,
                              hipStream_t stream)
{
    const int*   m     = (const int*)d_in[0];
    const float* emb   = (const float*)d_in[1];
    const float* W_ih  = (const float*)d_in[2];
    const float* W_hh  = (const float*)d_in[3];
    const float* b_ih  = (const float*)d_in[4];
    const float* b_hh  = (const float*)d_in[5];
    const float* W_out = (const float*)d_in[6];
    const float* b_out = (const float*)d_in[7];
    float* out = (float*)d_out;

    char* w = (char*)d_ws;
    size_t off = 0;
    auto alloc = [&](size_t bytes) {
        char* p = w + off;
        off = (off + bytes + 255) & ~(size_t)255;
        return p;
    };
    _Float16* emb16   = (_Float16*)alloc((size_t)VPAD_ * EMB_ * 2);
    _Float16* Wc16    = (_Float16*)alloc((size_t)G4H_ * KCAT_ * 2);
    _Float16* Wout16  = (_Float16*)alloc((size_t)NIMG_ * HID_ * 2);
    float*    biasp   = (float*)   alloc((size_t)G4H_ * 4);
    _Float16* Hseq    = (_Float16*)alloc((size_t)(T_ + 1) * B_ * HID_ * 2);  // 68 MB
    int*      tokperm = (int*)     alloc((size_t)B_ * T_ * 4);
    unsigned* flags   = (unsigned*)alloc((size_t)T_ * 4 * 64 * 4);   // 64 KB
    _Float16* PEx     = (_Float16*)alloc((size_t)VPAD_ * G4H_ * 2);  // 83 MB

    // 1) convert / permute / init (flags stay poisoned: magic differs per t)
    {
        const long long total = (long long)VOCAB_ * EMB_ + (long long)G4H_ * KCAT_ +
                                (long long)NIMG_ * HID_ + G4H_ +
                                (long long)B_ * HID_ + (long long)B_ * T_;
        convert_kernel<<<(int)((total + 255) / 256), 256, 0, stream>>>(
            m, emb, W_ih, W_hh, b_ih, b_hh, W_out,
            emb16, Wc16, Wout16, biasp, Hseq, tokperm);
    }

    // 2) PE table: emb @ W_ih^T + bias for all vocab rows (gate-packed)
    gemm_pe<<<dim3(VPAD_ / 128, G4H_ / 128), 256, 0, stream>>>(
        emb16, Wc16, biasp, PEx);

    // 3) entire recurrence in one persistent kernel (256 blocks, 1/CU)
    lstm_persistent<<<dim3(B_ / 128, G4H_ / 64), 256, 0, stream>>>(
        PEx, tokperm, Wc16, Hseq, flags);

    // 4) out = Hseq[T] @ W_out^T + b_out
    gemm_out<<<dim3(B_ / 64, NIMG_ / 128), 256, 0, stream>>>(
        Hseq + (size_t)T_ * B_ * HID_, Wout16, b_out, out, NIMG_, HID_);
}

// Round 10
// 856.138 us; speedup vs baseline: 1.1136x; 1.1136x over previous
//
#include <hip/hip_runtime.h>
#include <cstdint>

#define B_    512
#define T_    64
#define VOCAB_ 10000
#define VPAD_ 10112     // vocab padded to 128
#define EMB_  512
#define HID_  1024
#define G4H_  4096      // 4*HID
#define KCAT_ 1536      // EMB + HID
#define NIMG_ 2048

typedef _Float16 half8 __attribute__((ext_vector_type(8)));
typedef _Float16 half4 __attribute__((ext_vector_type(4)));
typedef float floatx4 __attribute__((ext_vector_type(4)));

// Async global->LDS, 16B per lane. LDS dest = wave-uniform base (HW adds
// lane*16). Per-lane SOURCE address is free (gather OK).
__device__ __forceinline__ void async_copy16(void* lds_uniform, const void* gsrc) {
    __builtin_amdgcn_global_load_lds(
        (__attribute__((address_space(1))) void*)(uintptr_t)gsrc,
        (__attribute__((address_space(3))) void*)(uint32_t)(uintptr_t)lds_uniform,
        16, 0, 0);
}

__device__ __forceinline__ float fsig(float x)  { return 1.0f / (1.0f + __expf(-x)); }
__device__ __forceinline__ float ftanh(float x) { return 1.0f - 2.0f / (__expf(2.0f * x) + 1.0f); }

// Gate-interleaved weight-row permutation:
//   n_perm = jblk*64 + gate*16 + jlo   <->   n_orig = gate*HID + (jblk*16 + jlo)

// ---------------------------------------------------------------------------
// One-time: emb->f16, Wc16 = permuted [W_ih|W_hh] (4096 x 1536), Wout16,
// biasp = permuted (b_ih+b_hh), Hseq[0] = 0, tokperm[t*B+b] = m[b][t].
// ---------------------------------------------------------------------------
__global__ __launch_bounds__(256) void convert_kernel(
    const int* __restrict__ m, const float* __restrict__ emb,
    const float* __restrict__ W_ih, const float* __restrict__ W_hh,
    const float* __restrict__ b_ih, const float* __restrict__ b_hh,
    const float* __restrict__ W_out,
    _Float16* __restrict__ emb16, _Float16* __restrict__ Wc16,
    _Float16* __restrict__ Wout16, float* __restrict__ biasp,
    _Float16* __restrict__ Hseq, int* __restrict__ tokperm)
{
    const long long EMB_N = (long long)VOCAB_ * EMB_;
    const long long WC_N  = (long long)G4H_ * KCAT_;
    const long long WO_N  = (long long)NIMG_ * HID_;
    const long long BI_N  = G4H_;
    const long long ST_N  = (long long)B_ * HID_;
    const long long TK_N  = (long long)B_ * T_;

    long long i = (long long)blockIdx.x * 256 + threadIdx.x;
    if (i < EMB_N) { emb16[i] = (_Float16)emb[i]; return; }
    i -= EMB_N;
    if (i < WC_N) {
        int n_perm = (int)(i / KCAT_);
        int k      = (int)(i % KCAT_);
        int gate = (n_perm >> 4) & 3;
        int j    = (n_perm >> 6) * 16 + (n_perm & 15);
        int n_orig = gate * HID_ + j;
        float v = (k < EMB_) ? W_ih[(size_t)n_orig * EMB_ + k]
                             : W_hh[(size_t)n_orig * HID_ + (k - EMB_)];
        Wc16[i] = (_Float16)v;
        return;
    }
    i -= WC_N;
    if (i < WO_N) { Wout16[i] = (_Float16)W_out[i]; return; }
    i -= WO_N;
    if (i < BI_N) {
        int n_perm = (int)i;
        int gate = (n_perm >> 4) & 3;
        int j    = (n_perm >> 6) * 16 + (n_perm & 15);
        biasp[i] = b_ih[gate * HID_ + j] + b_hh[gate * HID_ + j];
        return;
    }
    i -= BI_N;
    if (i < ST_N) { Hseq[i] = (_Float16)0.0f; return; }   // Hseq[0] = h_0 = 0
    i -= ST_N;
    if (i < TK_N) {
        int t = (int)(i / B_), b = (int)(i % B_);
        tokperm[i] = m[(size_t)b * T_ + t];
    }
}

// ---------------------------------------------------------------------------
// PE table GEMM: PEx[v][jblk*64 + jlo*4 + g] = emb[v] @ W_ih_perm^T + biasp
// (gate-packed: persistent kernel's acc-init is one 8B load per row).
// ---------------------------------------------------------------------------
__global__ __launch_bounds__(256) void gemm_pe(
    const _Float16* __restrict__ emb16, const _Float16* __restrict__ Wc16,
    const float* __restrict__ biasp, _Float16* __restrict__ PEx)
{
    __shared__ __align__(16) _Float16 As[128 * 32];
    __shared__ __align__(16) _Float16 Bs[128 * 32];

    const int tid  = threadIdx.x;
    const int wid  = tid >> 6;
    const int lane = tid & 63;
    const int lcol = lane & 15;
    const int quad = lane >> 4;
    const int wm   = wid >> 1;
    const int wn   = wid & 1;

    const int r0 = blockIdx.x * 128;
    const int n0 = blockIdx.y * 128;

    floatx4 acc[4][4];
#pragma unroll
    for (int i = 0; i < 4; ++i)
#pragma unroll
        for (int j = 0; j < 4; ++j) acc[i][j] = (floatx4){0.f, 0.f, 0.f, 0.f};

    const int ar = tid >> 2;
    const int kq = tid & 3;

    for (int k0 = 0; k0 < EMB_; k0 += 32) {
        async_copy16((char*)As + (wid << 10),
                     emb16 + (size_t)(r0 + ar) * EMB_ + (k0 + kq * 8));
        async_copy16((char*)As + 4096 + (wid << 10),
                     emb16 + (size_t)(r0 + 64 + ar) * EMB_ + (k0 + kq * 8));
        async_copy16((char*)Bs + (wid << 10),
                     Wc16 + (size_t)(n0 + ar) * KCAT_ + (k0 + kq * 8));
        async_copy16((char*)Bs + 4096 + (wid << 10),
                     Wc16 + (size_t)(n0 + 64 + ar) * KCAT_ + (k0 + kq * 8));
        __syncthreads();

        half8 af[4], bf[4];
#pragma unroll
        for (int mi = 0; mi < 4; ++mi)
            af[mi] = *(const half8*)&As[(wm * 64 + mi * 16 + lcol) * 32 + quad * 8];
#pragma unroll
        for (int ni = 0; ni < 4; ++ni)
            bf[ni] = *(const half8*)&Bs[(wn * 64 + ni * 16 + lcol) * 32 + quad * 8];
#pragma unroll
        for (int mi = 0; mi < 4; ++mi)
#pragma unroll
            for (int ni = 0; ni < 4; ++ni)
                acc[mi][ni] = __builtin_amdgcn_mfma_f32_16x16x32_f16(
                    af[mi], bf[ni], acc[mi][ni], 0, 0, 0);
        __syncthreads();
    }

    const int jblk = (n0 + wn * 64) >> 6;
    float bv[4];
#pragma unroll
    for (int ni = 0; ni < 4; ++ni) bv[ni] = biasp[n0 + wn * 64 + ni * 16 + lcol];
#pragma unroll
    for (int mi = 0; mi < 4; ++mi) {
#pragma unroll
        for (int r = 0; r < 4; ++r) {
            const int row = r0 + wm * 64 + mi * 16 + quad * 4 + r;
            half4 v;
#pragma unroll
            for (int ni = 0; ni < 4; ++ni)
                v[ni] = (_Float16)(acc[mi][ni][r] + bv[ni]);
            *(half4*)(PEx + (size_t)row * G4H_ + jblk * 64 + lcol * 4) = v;
        }
    }
}

// ---------------------------------------------------------------------------
// Persistent LSTM. Grid (4,64)=256 blocks, 1/CU. Tile 128 rows x 64 perm-cols.
// R9 = R7 structure (zero-fence freshness scheme, straight depth-8 K-loop)
// + TWO-PHASE monolithic wait with uniform chunk rotation:
//   rot = (by&1)*16. Chunks [rot,rot+16) need producers by'=2rot..2rot+31
//   -> wait(32-producer mask), prime 8 loads, wait(other 32), then R7's
//   exact 32-iter pipeline with cs=(s+rot)&31 (wave-uniform SALU).
//   No polling inside the loop (R8's mistake). Replaces E[max64] with
//   ~E[max32]; half the consumers start on the opposite half.
// ---------------------------------------------------------------------------
__global__ __launch_bounds__(256, 1) void lstm_persistent(
    const _Float16* __restrict__ PEx, const int* __restrict__ tokperm,
    const _Float16* __restrict__ Wc16,
    _Float16* __restrict__ Hseq,
    unsigned* __restrict__ flags)
{
    __shared__ __align__(16) char Wlds[131072];   // frag-major, 128 KB

    const int tid  = threadIdx.x;
    const int wid  = tid >> 6;
    const int lane = tid & 63;
    const int lcol = lane & 15;
    const int quad = lane >> 4;
    const int bx   = blockIdx.x;
    const int b0   = bx * 128;
    const int by   = blockIdx.y;
    const int n0   = by * 64;
    const int rot  = (by & 1) * 16;   // chunk rotation (wave-uniform)

    // One-time cross-launch safety: clear any stale lines (cheap, once).
    __builtin_amdgcn_fence(__ATOMIC_ACQUIRE, "agent");

    // ---- W one-time load, fragment-major: Wlds[((s*4+g)*64+lane)*16] holds
    // B-frag element W[n0+g*16+lcol][EMB + s*32+quad*8 ..+7]. Wave wid
    // handles s in [wid*8, wid*8+8). Conflict-free by construction.
    for (int si = 0; si < 8; ++si) {
        const int s = wid * 8 + si;
#pragma unroll
        for (int g = 0; g < 4; ++g) {
            half8 v = *(const half8*)(Wc16 + (size_t)(n0 + g * 16 + lcol) * KCAT_
                                      + EMB_ + s * 32 + quad * 8);
            *(half8*)(Wlds + (((s * 4 + g) << 6) + lane) * 16) = v;
        }
    }

    // Thread's outputs: rows wid*32+mi*16+quad*4+r (mi 0..1), col j=by*16+lcol
    float cst[2][4] = {{0.f, 0.f, 0.f, 0.f}, {0.f, 0.f, 0.f, 0.f}};
    half4 pe[2][4];

    // PE prefetch for t=0
#pragma unroll
    for (int mi = 0; mi < 2; ++mi)
#pragma unroll
        for (int r = 0; r < 4; ++r) {
            const int row = wid * 32 + mi * 16 + quad * 4 + r;
            const int tk = tokperm[b0 + row];
            pe[mi][r] = *(const half4*)(PEx + (size_t)tk * G4H_ + by * 64 + lcol * 4);
        }

    __syncthreads();  // W in LDS visible to all waves

    const int wrow = wid * 32;
    // producer mask for chunks [rot, rot+16): by' = 2*rot .. 2*rot+31
    const unsigned long long mA =
        rot ? 0xFFFFFFFF00000000ull : 0x00000000FFFFFFFFull;

    for (int t = 0; t < T_; ++t) {
        const _Float16* h_prev = Hseq + (size_t)t * (B_ * HID_);
        _Float16*       h_next = Hseq + (size_t)(t + 1) * (B_ * HID_);

        const unsigned want = 0x5AB00000u + (unsigned)(t - 1);
        const unsigned* f = flags + ((size_t)(t > 0 ? t - 1 : 0) * 4 + bx) * 64;

        unsigned long long rdy = (t == 0) ? ~0ull : 0ull;
        auto waitm = [&](unsigned long long need) {
            if ((rdy & need) == need) return;
            for (;;) {
                rdy = __ballot((int)(__hip_atomic_load(&f[lane], __ATOMIC_RELAXED,
                                                       __HIP_MEMORY_SCOPE_AGENT) == want));
                if ((rdy & need) == need) break;
                __builtin_amdgcn_s_sleep(1);
            }
            asm volatile("" ::: "memory");  // no hoisting of h loads above poll
        };

        // A-fragment source rows (plain cached loads on FRESH lines)
        const _Float16* arow0 = h_prev + (size_t)(b0 + wrow + lcol) * HID_ + quad * 8;
        const _Float16* arow1 = arow0 + (size_t)16 * HID_;

        floatx4 acc[2][4];
#pragma unroll
        for (int mi = 0; mi < 2; ++mi)
#pragma unroll
            for (int g = 0; g < 4; ++g)
#pragma unroll
                for (int r = 0; r < 4; ++r)
                    acc[mi][g][r] = (float)pe[mi][r][g];

        // ---- phase A wait, prime pipeline on first-half chunks ----
        waitm(mA);
        half8 pa0[8], pa1[8];
#pragma unroll
        for (int c = 0; c < 8; ++c) {
            const int cs = (c + rot) & 31;   // c<8, rot<=16 -> first half
            pa0[c] = *(const half8*)(arow0 + cs * 32);
            pa1[c] = *(const half8*)(arow1 + cs * 32);
        }
        // ---- phase B wait (16 loads already in flight) ----
        waitm(~mA);

        // ---- straight depth-8 pipeline over 32 k32 iters (R7 structure) ----
#pragma unroll
        for (int s = 0; s < 32; ++s) {
            const int cs = (s + rot) & 31;
            const half8 a0 = pa0[s & 7];
            const half8 a1 = pa1[s & 7];
            if (s + 8 < 32) {
                const int cs8 = (s + 8 + rot) & 31;
                pa0[s & 7] = *(const half8*)(arow0 + cs8 * 32);
                pa1[s & 7] = *(const half8*)(arow1 + cs8 * 32);
            }
#pragma unroll
            for (int g = 0; g < 4; ++g) {
                const half8 bw = *(const half8*)(Wlds + (((cs * 4 + g) << 6) + lane) * 16);
                acc[0][g] = __builtin_amdgcn_mfma_f32_16x16x32_f16(a0, bw, acc[0][g], 0, 0, 0);
                acc[1][g] = __builtin_amdgcn_mfma_f32_16x16x32_f16(a1, bw, acc[1][g], 0, 0, 0);
            }
        }

        // ---- fused LSTM cell; h written WRITE-THROUGH to LLC (2B relaxed
        // agent atomic stores; no wbl2 needed at publish) ----
#pragma unroll
        for (int mi = 0; mi < 2; ++mi)
#pragma unroll
            for (int r = 0; r < 4; ++r) {
                const int row = wrow + mi * 16 + quad * 4 + r;
                const float iv = fsig(acc[mi][0][r]);
                const float fv = fsig(acc[mi][1][r]);
                const float gv = ftanh(acc[mi][2][r]);
                const float ov = fsig(acc[mi][3][r]);
                cst[mi][r] = fv * cst[mi][r] + iv * gv;
                const _Float16 hv = (_Float16)(ov * ftanh(cst[mi][r]));
                unsigned short us = __builtin_bit_cast(unsigned short, hv);
                __hip_atomic_store(
                    (unsigned short*)&h_next[(size_t)(b0 + row) * HID_ + by * 16 + lcol],
                    us, __ATOMIC_RELAXED, __HIP_MEMORY_SCOPE_AGENT);
            }

        // ---- publish: drain stores (syncthreads waits vmcnt 0), then one
        // relaxed flag store by tid0. NO fences. ----
        __syncthreads();
        if (tid == 0) {
            __hip_atomic_store(&flags[((size_t)t * 4 + bx) * 64 + by],
                               0x5AB00000u + (unsigned)t,
                               __ATOMIC_RELAXED, __HIP_MEMORY_SCOPE_AGENT);
        }

        // PE prefetch for t+1 (read-only cached data; overlaps others' polls)
        if (t + 1 < T_) {
#pragma unroll
            for (int mi = 0; mi < 2; ++mi)
#pragma unroll
                for (int r = 0; r < 4; ++r) {
                    const int row = wrow + mi * 16 + quad * 4 + r;
                    const int tk = tokperm[(t + 1) * B_ + b0 + row];
                    pe[mi][r] = *(const half4*)(PEx + (size_t)tk * G4H_ + by * 64 + lcol * 4);
                }
        }
    }
}

// ---------------------------------------------------------------------------
// Final projection GEMM (unpermuted): Out = h @ Wout16^T + b_out
// ---------------------------------------------------------------------------
__global__ __launch_bounds__(256) void gemm_out(
    const _Float16* __restrict__ A, const _Float16* __restrict__ Bw,
    const float* __restrict__ bias, float* __restrict__ Out, int N, int K)
{
    __shared__ __align__(16) _Float16 As[64 * 32];
    __shared__ __align__(16) _Float16 Bs[128 * 32];

    const int tid  = threadIdx.x;
    const int wid  = tid >> 6;
    const int lane = tid & 63;
    const int lcol = lane & 15;
    const int quad = lane >> 4;
    const int wm   = wid >> 1;
    const int wn   = wid & 1;

    const int b0 = blockIdx.x * 64;
    const int n0 = blockIdx.y * 128;

    floatx4 acc[2][4];
#pragma unroll
    for (int i = 0; i < 2; ++i)
#pragma unroll
        for (int j = 0; j < 4; ++j) acc[i][j] = (floatx4){0.f, 0.f, 0.f, 0.f};

    const int ar = tid >> 2;
    const int kq = tid & 3;

    for (int k0 = 0; k0 < K; k0 += 32) {
        async_copy16((char*)As + (wid << 10), A + (size_t)(b0 + ar) * K + (k0 + kq * 8));
        async_copy16((char*)Bs + (wid << 10), Bw + (size_t)(n0 + ar) * K + (k0 + kq * 8));
        async_copy16((char*)Bs + 4096 + (wid << 10),
                     Bw + (size_t)(n0 + 64 + ar) * K + (k0 + kq * 8));
        __syncthreads();

        half8 af[2], bfr[4];
#pragma unroll
        for (int mi = 0; mi < 2; ++mi)
            af[mi] = *(const half8*)&As[(wm * 32 + mi * 16 + lcol) * 32 + quad * 8];
#pragma unroll
        for (int ni = 0; ni < 4; ++ni)
            bfr[ni] = *(const half8*)&Bs[(wn * 64 + ni * 16 + lcol) * 32 + quad * 8];
#pragma unroll
        for (int mi = 0; mi < 2; ++mi)
#pragma unroll
            for (int ni = 0; ni < 4; ++ni)
                acc[mi][ni] = __builtin_amdgcn_mfma_f32_16x16x32_f16(
                    af[mi], bfr[ni], acc[mi][ni], 0, 0, 0);
        __syncthreads();
    }

#pragma unroll
    for (int mi = 0; mi < 2; ++mi) {
#pragma unroll
        for (int ni = 0; ni < 4; ++ni) {
            const int row = b0 + wm * 32 + mi * 16 + quad * 4;
            const int col = n0 + wn * 64 + ni * 16 + lcol;
            const float bv = bias[col];
#pragma unroll
            for (int r = 0; r < 4; ++r)
                Out[(size_t)(row + r) * N + col] = acc[mi][ni][r] + bv;
        }
    }
}

// ---------------------------------------------------------------------------
extern "C" void kernel_launch(void* const* d_in, const int* in_sizes, int n_in,
                              void* d_out, int out_size, void* d_ws, size_t ws_size,
                              hipStream_t stream)
{
    const int*   m     = (const int*)d_in[0];
    const float* emb   = (const float*)d_in[1];
    const float* W_ih  = (const float*)d_in[2];
    const float* W_hh  = (const float*)d_in[3];
    const float* b_ih  = (const float*)d_in[4];
    const float* b_hh  = (const float*)d_in[5];
    const float* W_out = (const float*)d_in[6];
    const float* b_out = (const float*)d_in[7];
    float* out = (float*)d_out;

    char* w = (char*)d_ws;
    size_t off = 0;
    auto alloc = [&](size_t bytes) {
        char* p = w + off;
        off = (off + bytes + 255) & ~(size_t)255;
        return p;
    };
    _Float16* emb16   = (_Float16*)alloc((size_t)VPAD_ * EMB_ * 2);
    _Float16* Wc16    = (_Float16*)alloc((size_t)G4H_ * KCAT_ * 2);
    _Float16* Wout16  = (_Float16*)alloc((size_t)NIMG_ * HID_ * 2);
    float*    biasp   = (float*)   alloc((size_t)G4H_ * 4);
    _Float16* Hseq    = (_Float16*)alloc((size_t)(T_ + 1) * B_ * HID_ * 2);  // 68 MB
    int*      tokperm = (int*)     alloc((size_t)B_ * T_ * 4);
    unsigned* flags   = (unsigned*)alloc((size_t)T_ * 4 * 64 * 4);   // 64 KB
    _Float16* PEx     = (_Float16*)alloc((size_t)VPAD_ * G4H_ * 2);  // 83 MB

    // 1) convert / permute / init (flags stay poisoned: magic differs per t)
    {
        const long long total = (long long)VOCAB_ * EMB_ + (long long)G4H_ * KCAT_ +
                                (long long)NIMG_ * HID_ + G4H_ +
                                (long long)B_ * HID_ + (long long)B_ * T_;
        convert_kernel<<<(int)((total + 255) / 256), 256, 0, stream>>>(
            m, emb, W_ih, W_hh, b_ih, b_hh, W_out,
            emb16, Wc16, Wout16, biasp, Hseq, tokperm);
    }

    // 2) PE table: emb @ W_ih^T + bias for all vocab rows (gate-packed)
    gemm_pe<<<dim3(VPAD_ / 128, G4H_ / 128), 256, 0, stream>>>(
        emb16, Wc16, biasp, PEx);

    // 3) entire recurrence in one persistent kernel (256 blocks, 1/CU)
    lstm_persistent<<<dim3(B_ / 128, G4H_ / 64), 256, 0, stream>>>(
        PEx, tokperm, Wc16, Hseq, flags);

    // 4) out = Hseq[T] @ W_out^T + b_out
    gemm_out<<<dim3(B_ / 64, NIMG_ / 128), 256, 0, stream>>>(
        Hseq + (size_t)T_ * B_ * HID_, Wout16, b_out, out, NIMG_, HID_);
}